// Round 1
// baseline (396.066 us; speedup 1.0000x reference)
//
#include <hip/hip_runtime.h>
#include <hip/hip_bf16.h>

#define NN 8192
#define NE 262144

typedef __attribute__((ext_vector_type(8))) short bf16x8;
typedef __attribute__((ext_vector_type(4))) float f32x4;
typedef unsigned short u16;

__device__ inline u16 f2b(float f) {
  unsigned u = __float_as_uint(f);
  unsigned r = u + 0x7FFF + ((u >> 16) & 1);   // RNE to bf16
  return (u16)(r >> 16);
}
__device__ inline float b2f(u16 b) {
  return __uint_as_float(((unsigned)b) << 16);
}

// ---------- converts ----------
__global__ void split_f32_bf16(const float* __restrict__ in, u16* __restrict__ hi,
                               u16* __restrict__ lo, int n) {
  int i = blockIdx.x * blockDim.x + threadIdx.x;
  if (i >= n) return;
  float v = in[i];
  u16 h = f2b(v);
  hi[i] = h;
  lo[i] = f2b(v - b2f(h));
}

// W23[k][j] = (j<128 ? W2[k][j] : W3[k][j-128]),  k<256, j<256
__global__ void build_w23(const float* __restrict__ W2, const float* __restrict__ W3,
                          u16* __restrict__ hi, u16* __restrict__ lo) {
  int i = blockIdx.x * blockDim.x + threadIdx.x;  // 65536
  int k = i >> 8, j = i & 255;
  float v = (j < 128) ? W2[(k << 7) + j] : W3[(k << 7) + (j - 128)];
  u16 h = f2b(v);
  hi[i] = h;
  lo[i] = f2b(v - b2f(h));
}

// ---------- CSR build ----------
__global__ void hist_kernel(const int* __restrict__ dst, int* __restrict__ deg) {
  int i = blockIdx.x * blockDim.x + threadIdx.x;
  if (i < NE) atomicAdd(&deg[dst[i]], 1);
}

__global__ void scan_kernel(const int* __restrict__ deg, int* __restrict__ rowptr,
                            int* __restrict__ cursor) {
  __shared__ int sums[1024];
  int t = threadIdx.x;
  int loc[8];
  int s = 0;
#pragma unroll
  for (int j = 0; j < 8; ++j) { s += deg[t * 8 + j]; loc[j] = s; }
  sums[t] = s;
  __syncthreads();
  for (int off = 1; off < 1024; off <<= 1) {
    int v = (t >= off) ? sums[t - off] : 0;
    __syncthreads();
    sums[t] += v;
    __syncthreads();
  }
  int base = (t > 0) ? sums[t - 1] : 0;
  if (t == 0) rowptr[0] = 0;
#pragma unroll
  for (int j = 0; j < 8; ++j) {
    rowptr[t * 8 + j + 1] = base + loc[j];
    cursor[t * 8 + j] = base + (j ? loc[j - 1] : 0);
  }
}

__global__ void scatter_kernel(const int* __restrict__ src, const int* __restrict__ dst,
                               const float* __restrict__ w, int* cursor,
                               int* __restrict__ csr_src, float* __restrict__ csr_w) {
  int i = blockIdx.x * blockDim.x + threadIdx.x;
  if (i >= NE) return;
  int d = dst[i];
  int p = atomicAdd(&cursor[d], 1);
  csr_src[p] = src[i];
  csr_w[p] = w[i];
}

// ---------- split-precision bf16 MFMA GEMM: C = A(MxK) @ B(KxN), f32 out ----------
// block = 256 (4 waves), each wave one 16x16 C tile; grid = (M/64, N/16)
__global__ void gemm_split_kernel(const u16* __restrict__ Ah, const u16* __restrict__ Al,
                                  const u16* __restrict__ Bh, const u16* __restrict__ Bl,
                                  float* __restrict__ C, int M, int N, int K) {
  int wave = threadIdx.x >> 6, lane = threadIdx.x & 63;
  int r = lane & 15, g = lane >> 4;
  int row = blockIdx.x * 64 + wave * 16;
  int col0 = blockIdx.y * 16;
  f32x4 acc = {0.f, 0.f, 0.f, 0.f};
  for (int k0 = 0; k0 < K; k0 += 32) {
    int ka = k0 + g * 8;
    bf16x8 ah = *(const bf16x8*)(Ah + (size_t)(row + r) * K + ka);
    bf16x8 al = *(const bf16x8*)(Al + (size_t)(row + r) * K + ka);
    bf16x8 bh, bl;
#pragma unroll
    for (int j = 0; j < 8; ++j) {
      bh[j] = (short)Bh[(size_t)(ka + j) * N + col0 + r];
      bl[j] = (short)Bl[(size_t)(ka + j) * N + col0 + r];
    }
    acc = __builtin_amdgcn_mfma_f32_16x16x32_bf16(ah, bh, acc, 0, 0, 0);
    acc = __builtin_amdgcn_mfma_f32_16x16x32_bf16(al, bh, acc, 0, 0, 0);
    acc = __builtin_amdgcn_mfma_f32_16x16x32_bf16(ah, bl, acc, 0, 0, 0);
  }
#pragma unroll
  for (int t = 0; t < 4; ++t)
    C[(size_t)(row + g * 4 + t) * N + col0 + r] = acc[t];
}

// ---------- spmm (CSR, one block per dst node, 256 feature cols) ----------
__global__ void spmm_relu_kernel(const int* __restrict__ rowptr, const int* __restrict__ csr_src,
                                 const float* __restrict__ csr_w, const float* __restrict__ h,
                                 u16* __restrict__ oh, u16* __restrict__ ol) {
  int n = blockIdx.x, c = threadIdx.x;
  int e0 = rowptr[n], e1 = rowptr[n + 1];
  float acc = 0.f;
  for (int i = e0; i < e1; ++i)
    acc = fmaf(csr_w[i], h[(size_t)csr_src[i] * 256 + c], acc);
  acc = fmaxf(acc, 0.f);
  u16 hb = f2b(acc);
  oh[(size_t)n * 256 + c] = hb;
  ol[(size_t)n * 256 + c] = f2b(acc - b2f(hb));
}

__global__ void spmm_out_kernel(const int* __restrict__ rowptr, const int* __restrict__ csr_src,
                                const float* __restrict__ csr_w, const float* __restrict__ h,
                                float* __restrict__ mu, float* __restrict__ logvar,
                                float* __restrict__ z, u16* __restrict__ zb) {
  int n = blockIdx.x, c = threadIdx.x;
  int e0 = rowptr[n], e1 = rowptr[n + 1];
  float acc = 0.f;
  for (int i = e0; i < e1; ++i)
    acc = fmaf(csr_w[i], h[(size_t)csr_src[i] * 256 + c], acc);
  if (c < 128) {
    mu[(size_t)n * 128 + c] = acc;
    z[(size_t)n * 128 + c] = acc;
    zb[(size_t)n * 128 + c] = f2b(acc);
  } else {
    logvar[(size_t)n * 128 + (c - 128)] = acc;
  }
}

// ---------- adj = Z @ Z^T, Z [8192][128] bf16, C [8192][8192] f32 ----------
// block = 256 (4 waves); wave covers 16x64 strip; block tile 64x64; grid (128,128)
__global__ void zzt_kernel(const u16* __restrict__ Z, float* __restrict__ C) {
  int wave = threadIdx.x >> 6, lane = threadIdx.x & 63;
  int r = lane & 15, g = lane >> 4;
  int i0 = blockIdx.x * 64 + wave * 16;
  int j0 = blockIdx.y * 64;
  f32x4 zero = {0.f, 0.f, 0.f, 0.f};
  f32x4 acc[4];
#pragma unroll
  for (int t = 0; t < 4; ++t) acc[t] = zero;
#pragma unroll
  for (int k0 = 0; k0 < 128; k0 += 32) {
    int ka = k0 + g * 8;
    bf16x8 a = *(const bf16x8*)(Z + (size_t)(i0 + r) * 128 + ka);
#pragma unroll
    for (int t = 0; t < 4; ++t) {
      bf16x8 b = *(const bf16x8*)(Z + (size_t)(j0 + t * 16 + r) * 128 + ka);
      acc[t] = __builtin_amdgcn_mfma_f32_16x16x32_bf16(a, b, acc[t], 0, 0, 0);
    }
  }
#pragma unroll
  for (int t = 0; t < 4; ++t)
#pragma unroll
    for (int q = 0; q < 4; ++q)
      C[(size_t)(i0 + g * 4 + q) * NN + j0 + t * 16 + r] = acc[t][q];
}

extern "C" void kernel_launch(void* const* d_in, const int* in_sizes, int n_in,
                              void* d_out, int out_size, void* d_ws, size_t ws_size,
                              hipStream_t stream) {
  const float* x  = (const float*)d_in[0];
  const int*   ei = (const int*)d_in[1];
  const float* ew = (const float*)d_in[2];
  const float* W1 = (const float*)d_in[3];
  const float* W2 = (const float*)d_in[4];
  const float* W3 = (const float*)d_in[5];

  float* out    = (float*)d_out;
  float* adj    = out;                                   // [8192,8192]
  float* mu     = out + (size_t)NN * NN;                 // [8192,128]
  float* logv   = mu + (size_t)NN * 128;                 // [8192,128]
  float* z      = logv + (size_t)NN * 128;               // [8192,128]

  const int* srcp = ei;
  const int* dstp = ei + NE;

  char* ws = (char*)d_ws;
  size_t off = 0;
  auto alloc = [&](size_t b) -> void* {
    void* p = ws + off;
    off = (off + b + 255) & ~(size_t)255;
    return p;
  };
  u16* xh   = (u16*)alloc((size_t)NN * 512 * 2);
  u16* xl   = (u16*)alloc((size_t)NN * 512 * 2);
  u16* W1h  = (u16*)alloc(512 * 256 * 2);
  u16* W1l  = (u16*)alloc(512 * 256 * 2);
  u16* W23h = (u16*)alloc(256 * 256 * 2);
  u16* W23l = (u16*)alloc(256 * 256 * 2);
  float* h0 = (float*)alloc((size_t)NN * 256 * 4);
  u16* h1h  = (u16*)alloc((size_t)NN * 256 * 2);
  u16* h1l  = (u16*)alloc((size_t)NN * 256 * 2);
  float* H2 = (float*)alloc((size_t)NN * 256 * 4);
  u16* zb   = (u16*)alloc((size_t)NN * 128 * 2);
  int* deg      = (int*)alloc(NN * 4);
  int* rowptr   = (int*)alloc((NN + 1) * 4);
  int* cursor   = (int*)alloc(NN * 4);
  int* csr_src  = (int*)alloc((size_t)NE * 4);
  float* csr_w  = (float*)alloc((size_t)NE * 4);

  hipMemsetAsync(deg, 0, NN * 4, stream);

  // converts
  split_f32_bf16<<<(NN * 512 + 255) / 256, 256, 0, stream>>>(x, xh, xl, NN * 512);
  split_f32_bf16<<<(512 * 256 + 255) / 256, 256, 0, stream>>>(W1, W1h, W1l, 512 * 256);
  build_w23<<<(256 * 256) / 256, 256, 0, stream>>>(W2, W3, W23h, W23l);

  // CSR build
  hist_kernel<<<NE / 256, 256, 0, stream>>>(dstp, deg);
  scan_kernel<<<1, 1024, 0, stream>>>(deg, rowptr, cursor);
  scatter_kernel<<<NE / 256, 256, 0, stream>>>(srcp, dstp, ew, cursor, csr_src, csr_w);

  // h0 = x @ W1
  gemm_split_kernel<<<dim3(NN / 64, 256 / 16), 256, 0, stream>>>(xh, xl, W1h, W1l, h0,
                                                                 NN, 256, 512);
  // h1 = relu(spmm(h0)) -> bf16 hi/lo
  spmm_relu_kernel<<<NN, 256, 0, stream>>>(rowptr, csr_src, csr_w, h0, h1h, h1l);
  // H2 = h1 @ [W2|W3]
  gemm_split_kernel<<<dim3(NN / 64, 256 / 16), 256, 0, stream>>>(h1h, h1l, W23h, W23l, H2,
                                                                 NN, 256, 256);
  // mu/logvar = spmm(H2); z = mu; zb = bf16(mu)
  spmm_out_kernel<<<NN, 256, 0, stream>>>(rowptr, csr_src, csr_w, H2, mu, logv, z, zb);
  // adj = z @ z^T
  zzt_kernel<<<dim3(NN / 64, NN / 64), 256, 0, stream>>>(zb, adj);
}

// Round 2
// 264.600 us; speedup vs baseline: 1.4968x; 1.4968x over previous
//
#include <hip/hip_runtime.h>
#include <hip/hip_bf16.h>

#define NN 8192
#define NE 262144

typedef __attribute__((ext_vector_type(8))) short bf16x8;
typedef __attribute__((ext_vector_type(4))) float f32x4;
typedef __attribute__((ext_vector_type(16))) float f32x16;
typedef unsigned short u16;
typedef __attribute__((ext_vector_type(4))) u16 u16x4;

__device__ inline u16 f2b(float f) {
  unsigned u = __float_as_uint(f);
  unsigned r = u + 0x7FFF + ((u >> 16) & 1);   // RNE to bf16
  return (u16)(r >> 16);
}
__device__ inline float b2f(u16 b) {
  return __uint_as_float(((unsigned)b) << 16);
}

// ---------- converts ----------
__global__ void split_f32_bf16(const float* __restrict__ in, u16* __restrict__ hi,
                               u16* __restrict__ lo, int n) {
  int i = blockIdx.x * blockDim.x + threadIdx.x;
  if (i >= n) return;
  float v = in[i];
  u16 h = f2b(v);
  hi[i] = h;
  lo[i] = f2b(v - b2f(h));
}

// W1 [K=512][N=256] row-major -> col-major [256][512] hi/lo
__global__ void splitT_w1(const float* __restrict__ in, u16* __restrict__ hi,
                          u16* __restrict__ lo) {
  int i = blockIdx.x * blockDim.x + threadIdx.x;  // 512*256
  int k = i >> 8, n = i & 255;
  float v = in[i];
  u16 h = f2b(v);
  hi[(size_t)n * 512 + k] = h;
  lo[(size_t)n * 512 + k] = f2b(v - b2f(h));
}

// W23 col-major [256 cols][256 k]: col j<128 = W2[:,j], j>=128 = W3[:,j-128]
__global__ void build_w23T(const float* __restrict__ W2, const float* __restrict__ W3,
                           u16* __restrict__ hi, u16* __restrict__ lo) {
  int i = blockIdx.x * blockDim.x + threadIdx.x;  // 65536
  int k = i >> 8, j = i & 255;
  float v = (j < 128) ? W2[(k << 7) + j] : W3[(k << 7) + (j - 128)];
  u16 h = f2b(v);
  hi[(size_t)j * 256 + k] = h;
  lo[(size_t)j * 256 + k] = f2b(v - b2f(h));
}

// ---------- CSR build ----------
__global__ void hist_kernel(const int* __restrict__ dst, int* __restrict__ deg) {
  int i = blockIdx.x * blockDim.x + threadIdx.x;
  if (i < NE) atomicAdd(&deg[dst[i]], 1);
}

__global__ void scan_kernel(const int* __restrict__ deg, int* __restrict__ rowptr,
                            int* __restrict__ cursor) {
  __shared__ int sums[1024];
  int t = threadIdx.x;
  int loc[8];
  int s = 0;
#pragma unroll
  for (int j = 0; j < 8; ++j) { s += deg[t * 8 + j]; loc[j] = s; }
  sums[t] = s;
  __syncthreads();
  for (int off = 1; off < 1024; off <<= 1) {
    int v = (t >= off) ? sums[t - off] : 0;
    __syncthreads();
    sums[t] += v;
    __syncthreads();
  }
  int base = (t > 0) ? sums[t - 1] : 0;
  if (t == 0) rowptr[0] = 0;
#pragma unroll
  for (int j = 0; j < 8; ++j) {
    rowptr[t * 8 + j + 1] = base + loc[j];
    cursor[t * 8 + j] = base + (j ? loc[j - 1] : 0);
  }
}

__global__ void scatter_kernel(const int* __restrict__ src, const int* __restrict__ dst,
                               const float* __restrict__ w, int* cursor,
                               int* __restrict__ csr_src, float* __restrict__ csr_w) {
  int i = blockIdx.x * blockDim.x + threadIdx.x;
  if (i >= NE) return;
  int d = dst[i];
  int p = atomicAdd(&cursor[d], 1);
  csr_src[p] = src[i];
  csr_w[p] = w[i];
}

// ---------- split-precision GEMM: C = A(MxK) @ B(KxN), B pre-packed col-major ----
// block 256 thr / 4 waves; wave = 16 rows x 64 cols (4 col tiles); grid (M/64, N/64)
__global__ void gemm_split_kernel(const u16* __restrict__ Ah, const u16* __restrict__ Al,
                                  const u16* __restrict__ Bh, const u16* __restrict__ Bl,
                                  float* __restrict__ C, int M, int N, int K) {
  int wave = threadIdx.x >> 6, lane = threadIdx.x & 63;
  int r = lane & 15, kf = (lane >> 4) * 8;
  int row = blockIdx.x * 64 + wave * 16 + r;
  int col0 = blockIdx.y * 64;
  f32x4 acc[4] = {};
  for (int k0 = 0; k0 < K; k0 += 32) {
    int ka = k0 + kf;
    bf16x8 ah = *(const bf16x8*)(Ah + (size_t)row * K + ka);
    bf16x8 al = *(const bf16x8*)(Al + (size_t)row * K + ka);
#pragma unroll
    for (int t = 0; t < 4; ++t) {
      int col = col0 + t * 16 + r;
      bf16x8 bh = *(const bf16x8*)(Bh + (size_t)col * K + ka);
      bf16x8 bl = *(const bf16x8*)(Bl + (size_t)col * K + ka);
      acc[t] = __builtin_amdgcn_mfma_f32_16x16x32_bf16(ah, bh, acc[t], 0, 0, 0);
      acc[t] = __builtin_amdgcn_mfma_f32_16x16x32_bf16(al, bh, acc[t], 0, 0, 0);
      acc[t] = __builtin_amdgcn_mfma_f32_16x16x32_bf16(ah, bl, acc[t], 0, 0, 0);
    }
  }
  int orow = blockIdx.x * 64 + wave * 16 + (lane >> 4) * 4;
#pragma unroll
  for (int t = 0; t < 4; ++t)
#pragma unroll
    for (int q = 0; q < 4; ++q)
      C[(size_t)(orow + q) * N + col0 + t * 16 + r] = acc[t][q];
}

// ---------- spmm (CSR): 4 nodes/block, 64 lanes/node, float4 per lane ----------
__global__ void spmm_relu_kernel(const int* __restrict__ rowptr, const int* __restrict__ csr_src,
                                 const float* __restrict__ csr_w, const float* __restrict__ h,
                                 u16* __restrict__ oh, u16* __restrict__ ol) {
  int n = blockIdx.x * 4 + (threadIdx.x >> 6);
  int lane = threadIdx.x & 63;
  int c = lane * 4;
  int e0 = rowptr[n], e1 = rowptr[n + 1];
  f32x4 acc = {};
  for (int i = e0; i < e1; ++i) {
    float w = csr_w[i];
    f32x4 v = *(const f32x4*)(h + (size_t)csr_src[i] * 256 + c);
#pragma unroll
    for (int j = 0; j < 4; ++j) acc[j] = fmaf(w, v[j], acc[j]);
  }
  u16x4 vh, vl;
#pragma unroll
  for (int j = 0; j < 4; ++j) {
    float a = fmaxf(acc[j], 0.f);
    u16 hb = f2b(a);
    vh[j] = hb;
    vl[j] = f2b(a - b2f(hb));
  }
  *(u16x4*)(oh + (size_t)n * 256 + c) = vh;
  *(u16x4*)(ol + (size_t)n * 256 + c) = vl;
}

__global__ void spmm_out_kernel(const int* __restrict__ rowptr, const int* __restrict__ csr_src,
                                const float* __restrict__ csr_w, const float* __restrict__ h,
                                float* __restrict__ mu, float* __restrict__ logvar,
                                float* __restrict__ z, u16* __restrict__ zb) {
  int n = blockIdx.x * 4 + (threadIdx.x >> 6);
  int lane = threadIdx.x & 63;
  int c = lane * 4;
  int e0 = rowptr[n], e1 = rowptr[n + 1];
  f32x4 acc = {};
  for (int i = e0; i < e1; ++i) {
    float w = csr_w[i];
    f32x4 v = *(const f32x4*)(h + (size_t)csr_src[i] * 256 + c);
#pragma unroll
    for (int j = 0; j < 4; ++j) acc[j] = fmaf(w, v[j], acc[j]);
  }
  if (c < 128) {
    *(f32x4*)(mu + (size_t)n * 128 + c) = acc;
    *(f32x4*)(z + (size_t)n * 128 + c) = acc;
    u16x4 vb;
#pragma unroll
    for (int j = 0; j < 4; ++j) vb[j] = f2b(acc[j]);
    *(u16x4*)(zb + (size_t)n * 128 + c) = vb;
  } else {
    *(f32x4*)(logvar + (size_t)n * 128 + (c - 128)) = acc;
  }
}

// ---------- adj = Z @ Z^T, Z [8192][128] bf16, C [8192][8192] f32 ----------
// 128x128 block tile, 4 waves (2x2 quadrants of 64x64), 32x32x16 MFMA
__global__ void zzt_kernel(const u16* __restrict__ Z, float* __restrict__ C) {
  int wave = threadIdx.x >> 6, lane = threadIdx.x & 63;
  int wr = wave >> 1, wc = wave & 1;
  int i0 = blockIdx.x * 128 + wr * 64;
  int j0 = blockIdx.y * 128 + wc * 64;
  int lrow = lane & 31, lk = (lane >> 5) * 8;
  f32x16 acc00 = {}, acc01 = {}, acc10 = {}, acc11 = {};
#pragma unroll
  for (int k0 = 0; k0 < 128; k0 += 16) {
    bf16x8 a0 = *(const bf16x8*)(Z + (size_t)(i0 + lrow) * 128 + k0 + lk);
    bf16x8 a1 = *(const bf16x8*)(Z + (size_t)(i0 + 32 + lrow) * 128 + k0 + lk);
    bf16x8 b0 = *(const bf16x8*)(Z + (size_t)(j0 + lrow) * 128 + k0 + lk);
    bf16x8 b1 = *(const bf16x8*)(Z + (size_t)(j0 + 32 + lrow) * 128 + k0 + lk);
    acc00 = __builtin_amdgcn_mfma_f32_32x32x16_bf16(a0, b0, acc00, 0, 0, 0);
    acc01 = __builtin_amdgcn_mfma_f32_32x32x16_bf16(a0, b1, acc01, 0, 0, 0);
    acc10 = __builtin_amdgcn_mfma_f32_32x32x16_bf16(a1, b0, acc10, 0, 0, 0);
    acc11 = __builtin_amdgcn_mfma_f32_32x32x16_bf16(a1, b1, acc11, 0, 0, 0);
  }
  int rbase = 4 * (lane >> 5);
  int col = lane & 31;
#pragma unroll
  for (int reg = 0; reg < 16; ++reg) {
    int rr = (reg & 3) + 8 * (reg >> 2) + rbase;
    C[(size_t)(i0 + rr) * NN + j0 + col]           = acc00[reg];
    C[(size_t)(i0 + rr) * NN + j0 + 32 + col]      = acc01[reg];
    C[(size_t)(i0 + 32 + rr) * NN + j0 + col]      = acc10[reg];
    C[(size_t)(i0 + 32 + rr) * NN + j0 + 32 + col] = acc11[reg];
  }
}

extern "C" void kernel_launch(void* const* d_in, const int* in_sizes, int n_in,
                              void* d_out, int out_size, void* d_ws, size_t ws_size,
                              hipStream_t stream) {
  const float* x  = (const float*)d_in[0];
  const int*   ei = (const int*)d_in[1];
  const float* ew = (const float*)d_in[2];
  const float* W1 = (const float*)d_in[3];
  const float* W2 = (const float*)d_in[4];
  const float* W3 = (const float*)d_in[5];

  float* out    = (float*)d_out;
  float* adj    = out;                                   // [8192,8192]
  float* mu     = out + (size_t)NN * NN;                 // [8192,128]
  float* logv   = mu + (size_t)NN * 128;                 // [8192,128]
  float* z      = logv + (size_t)NN * 128;               // [8192,128]

  const int* srcp = ei;
  const int* dstp = ei + NE;

  char* ws = (char*)d_ws;
  size_t off = 0;
  auto alloc = [&](size_t b) -> void* {
    void* p = ws + off;
    off = (off + b + 255) & ~(size_t)255;
    return p;
  };
  u16* xh   = (u16*)alloc((size_t)NN * 512 * 2);
  u16* xl   = (u16*)alloc((size_t)NN * 512 * 2);
  u16* W1h  = (u16*)alloc(512 * 256 * 2);   // col-major [256][512]
  u16* W1l  = (u16*)alloc(512 * 256 * 2);
  u16* W23h = (u16*)alloc(256 * 256 * 2);   // col-major [256][256]
  u16* W23l = (u16*)alloc(256 * 256 * 2);
  float* h0 = (float*)alloc((size_t)NN * 256 * 4);
  u16* h1h  = (u16*)alloc((size_t)NN * 256 * 2);
  u16* h1l  = (u16*)alloc((size_t)NN * 256 * 2);
  float* H2 = (float*)alloc((size_t)NN * 256 * 4);
  u16* zb   = (u16*)alloc((size_t)NN * 128 * 2);
  int* deg      = (int*)alloc(NN * 4);
  int* rowptr   = (int*)alloc((NN + 1) * 4);
  int* cursor   = (int*)alloc(NN * 4);
  int* csr_src  = (int*)alloc((size_t)NE * 4);
  float* csr_w  = (float*)alloc((size_t)NE * 4);

  hipMemsetAsync(deg, 0, NN * 4, stream);

  // converts
  split_f32_bf16<<<(NN * 512 + 255) / 256, 256, 0, stream>>>(x, xh, xl, NN * 512);
  splitT_w1<<<(512 * 256) / 256, 256, 0, stream>>>(W1, W1h, W1l);
  build_w23T<<<(256 * 256) / 256, 256, 0, stream>>>(W2, W3, W23h, W23l);

  // CSR build
  hist_kernel<<<NE / 256, 256, 0, stream>>>(dstp, deg);
  scan_kernel<<<1, 1024, 0, stream>>>(deg, rowptr, cursor);
  scatter_kernel<<<NE / 256, 256, 0, stream>>>(srcp, dstp, ew, cursor, csr_src, csr_w);

  // h0 = x @ W1
  gemm_split_kernel<<<dim3(NN / 64, 256 / 64), 256, 0, stream>>>(xh, xl, W1h, W1l, h0,
                                                                 NN, 256, 512);
  // h1 = relu(spmm(h0)) -> bf16 hi/lo
  spmm_relu_kernel<<<NN / 4, 256, 0, stream>>>(rowptr, csr_src, csr_w, h0, h1h, h1l);
  // H2 = h1 @ [W2|W3]
  gemm_split_kernel<<<dim3(NN / 64, 256 / 64), 256, 0, stream>>>(h1h, h1l, W23h, W23l, H2,
                                                                 NN, 256, 256);
  // mu/logvar = spmm(H2); z = mu; zb = bf16(mu)
  spmm_out_kernel<<<NN / 4, 256, 0, stream>>>(rowptr, csr_src, csr_w, H2, mu, logv, z, zb);
  // adj = z @ z^T
  zzt_kernel<<<dim3(NN / 128, NN / 128), 256, 0, stream>>>(zb, adj);
}